// Round 6
// baseline (295.173 us; speedup 1.0000x reference)
//
#include <hip/hip_runtime.h>
#include <math.h>

#define HW    50176                // 224*224
#define HW4   12544                // HW/4
#define BATCH 128
#define NUM_CLASSES 1000
#define N4    (BATCH * HW4)        // 1,605,632 float4-groups
#define TPB   256
#define NBLOCKS (N4 / TPB)         // 6272 (exact)

typedef float v4f __attribute__((ext_vector_type(4)));

// ws layout (floats): ws[0] = pixel loss sum, ws[1] = class loss sum

__launch_bounds__(TPB)
__global__ void pixel_loss_kernel(const v4f* __restrict__ objects,
                                  const v4f* __restrict__ locs,
                                  const v4f* __restrict__ gt,
                                  const float* __restrict__ obj_coor_p,
                                  const float* __restrict__ no_obj_confi_p,
                                  float* __restrict__ ws) {
    const float coorW = *obj_coor_p;
    const float noW   = *no_obj_confi_p;

    const unsigned g   = blockIdx.x * TPB + threadIdx.x;   // float4-group id
    const unsigned b   = g / HW4;
    const unsigned hw4 = g - b * HW4;
    const unsigned gtb = b * (5 * HW4) + hw4;
    const unsigned lcb = b * (4 * HW4) + hw4;

    // ---- always-needed streams: objects + mask (51.4 MB total) ----
    const v4f o  = objects[g];
    const v4f m4 = gt[gtb];          // each element exactly 0.0f or 1.0f

    // log terms for all 4 pixels (branch-free select between obj/noobj)
    float acc = 0.0f;
#pragma unroll
    for (int j = 0; j < 4; ++j) {
        const float p = o[j];
        const float m = m4[j];
        const float a  = -noW * fmaxf(__logf(1.0f - p), -100.0f); // m==0 term
        const float nl = -fmaxf(__logf(p), -100.0f);              // m==1 term
        acc += fmaf(m, nl - a, a);
    }

    // ---- coord streams (205.6 MB) gated on the mask: only ~18.5% of lanes
    //      have an object pixel among their 4; exec-masked lanes issue no
    //      memory requests -> ~44% of coord cachelines never fetched ----
    if (m4[0] + m4[1] + m4[2] + m4[3] > 0.0f) {
        v4f sq = {0.f, 0.f, 0.f, 0.f};
#pragma unroll
        for (int c = 0; c < 4; ++c) {
            v4f d = locs[lcb + (unsigned)(c * HW4)] - gt[gtb + (unsigned)((1 + c) * HW4)];
            sq += d * d;
        }
        // weight per-pixel by exact 0/1 mask
        acc += coorW * (m4[0] * sq[0] + m4[1] * sq[1] +
                        m4[2] * sq[2] + m4[3] * sq[3]);
    }

    // ---- wave (64-lane) reduce, then cross-wave via LDS ----
#pragma unroll
    for (int off = 32; off > 0; off >>= 1)
        acc += __shfl_down(acc, off, 64);

    __shared__ float smem[4];
    const int lane = threadIdx.x & 63;
    const int wave = threadIdx.x >> 6;
    if (lane == 0) smem[wave] = acc;
    __syncthreads();
    if (threadIdx.x == 0)
        atomicAdd(&ws[0], smem[0] + smem[1] + smem[2] + smem[3]);
}

__global__ void class_loss_kernel(const float* __restrict__ scores,
                                  const int* __restrict__ label,
                                  float* __restrict__ ws) {
    const int b = blockIdx.x;
    const float* row = scores + b * NUM_CLASSES;

    __shared__ float red[4];
    __shared__ float s_bcast;
    const int lane = threadIdx.x & 63;
    const int wave = threadIdx.x >> 6;

    // --- max reduce ---
    float mx = -INFINITY;
    for (int i = threadIdx.x; i < NUM_CLASSES; i += blockDim.x)
        mx = fmaxf(mx, row[i]);
#pragma unroll
    for (int off = 32; off > 0; off >>= 1)
        mx = fmaxf(mx, __shfl_down(mx, off, 64));
    if (lane == 0) red[wave] = mx;
    __syncthreads();
    if (threadIdx.x == 0)
        s_bcast = fmaxf(fmaxf(red[0], red[1]), fmaxf(red[2], red[3]));
    __syncthreads();
    mx = s_bcast;

    // --- sum(exp) reduce ---
    float se = 0.0f;
    for (int i = threadIdx.x; i < NUM_CLASSES; i += blockDim.x)
        se += __expf(row[i] - mx);
#pragma unroll
    for (int off = 32; off > 0; off >>= 1)
        se += __shfl_down(se, off, 64);
    __syncthreads();   // protect red[] reuse
    if (lane == 0) red[wave] = se;
    __syncthreads();
    if (threadIdx.x == 0) {
        float lse = mx + logf(red[0] + red[1] + red[2] + red[3]);
        atomicAdd(&ws[1], -(row[label[b]] - lse));
    }
}

__global__ void finalize_kernel(const float* __restrict__ ws,
                                const float* __restrict__ img_class_weight_p,
                                float* __restrict__ out) {
    if (threadIdx.x == 0 && blockIdx.x == 0) {
        float img_class_loss = ws[1] / (float)BATCH;
        out[0] = img_class_weight_p[0] * img_class_loss + ws[0] / (float)BATCH;
    }
}

extern "C" void kernel_launch(void* const* d_in, const int* in_sizes, int n_in,
                              void* d_out, int out_size, void* d_ws, size_t ws_size,
                              hipStream_t stream) {
    const float* objects = (const float*)d_in[0];   // (B,H,W)
    const float* scores  = (const float*)d_in[1];   // (B,1000)
    const float* locs    = (const float*)d_in[2];   // (B,4,H,W)
    const int*   label   = (const int*)d_in[3];     // (B,)
    const float* gt      = (const float*)d_in[4];   // (B,5,H,W)
    const float* obj_coor         = (const float*)d_in[5];
    const float* no_obj_confi     = (const float*)d_in[6];
    const float* img_class_weight = (const float*)d_in[7];

    float* ws  = (float*)d_ws;
    float* out = (float*)d_out;

    hipMemsetAsync(ws, 0, 2 * sizeof(float), stream);

    pixel_loss_kernel<<<NBLOCKS, TPB, 0, stream>>>(
        (const v4f*)objects, (const v4f*)locs, (const v4f*)gt,
        obj_coor, no_obj_confi, ws);

    class_loss_kernel<<<BATCH, 256, 0, stream>>>(scores, label, ws);

    finalize_kernel<<<1, 64, 0, stream>>>(ws, img_class_weight, out);
}